// Round 6
// baseline (305.150 us; speedup 1.0000x reference)
//
#include <hip/hip_runtime.h>
#include <hip/hip_fp8.h>

typedef int   i32x4  __attribute__((ext_vector_type(4)));
typedef int   i32x8  __attribute__((ext_vector_type(8)));
typedef float f32x16 __attribute__((ext_vector_type(16)));

#define BS 4096
#define D 1024          // elements per row; also BYTES per row in fp8
#define M2 8192

#define BK 64           // K elements (= bytes) per K-step
#define NKT (D / BK)    // 16 K-steps
#define NT 64           // M2/128 tiles per dim
#define NBLK (NT * (NT + 1) / 2)   // 2080 upper-triangle blocks (2080 % 8 == 0)

// workspace layout (bytes) — keep round-4 offsets (known to fit)
#define OFF_Z      ((size_t)0)
#define OFF_SUMEXP ((size_t)M2 * D * 2)
#define OFF_POS    (OFF_SUMEXP + (size_t)M2 * 4)
#define OFF_DIO    (OFF_POS + (size_t)M2 * 4)
#define OFF_DJO    (OFF_DIO + (size_t)BS * 4)

static __device__ __forceinline__ void gload_lds16(const void* g, void* l) {
  __builtin_amdgcn_global_load_lds(
      (__attribute__((address_space(1))) void*)(uintptr_t)g,
      (__attribute__((address_space(3))) void*)(unsigned int)(uintptr_t)l,
      16, 0, 0);
}

// ---------------- kernel 1: normalize rows, emit fp8 Z, per-row dots, zero sumexp ----------------
__global__ __launch_bounds__(256) void prep_kernel(
    const float* __restrict__ zi, const float* __restrict__ zj,
    const float* __restrict__ zo, unsigned char* __restrict__ Z,
    float* __restrict__ dio, float* __restrict__ djo,
    float* __restrict__ sumexp) {
  const int r = blockIdx.x;
  const int tid = threadIdx.x;
  if (tid < 2) sumexp[2 * r + tid] = 0.f;
  const float4 vi = ((const float4*)(zi + (size_t)r * D))[tid];
  const float4 vj = ((const float4*)(zj + (size_t)r * D))[tid];
  const float4 vo = ((const float4*)(zo + (size_t)r * D))[tid];

  float s[5];
  s[0] = vi.x * vi.x + vi.y * vi.y + vi.z * vi.z + vi.w * vi.w;
  s[1] = vj.x * vj.x + vj.y * vj.y + vj.z * vj.z + vj.w * vj.w;
  s[2] = vo.x * vo.x + vo.y * vo.y + vo.z * vo.z + vo.w * vo.w;
  s[3] = vi.x * vo.x + vi.y * vo.y + vi.z * vo.z + vi.w * vo.w;
  s[4] = vj.x * vo.x + vj.y * vo.y + vj.z * vo.z + vj.w * vo.w;

#pragma unroll
  for (int k = 0; k < 5; ++k)
#pragma unroll
    for (int o = 32; o; o >>= 1) s[k] += __shfl_xor(s[k], o);

  __shared__ float red[4][5];
  const int w = tid >> 6, lane = tid & 63;
  if (lane == 0) {
#pragma unroll
    for (int k = 0; k < 5; ++k) red[w][k] = s[k];
  }
  __syncthreads();
  float tot[5];
#pragma unroll
  for (int k = 0; k < 5; ++k)
    tot[k] = red[0][k] + red[1][k] + red[2][k] + red[3][k];

  const float rsi = 1.0f / sqrtf(tot[0]);
  const float rsj = 1.0f / sqrtf(tot[1]);
  const float rso = 1.0f / sqrtf(tot[2]);

  uchar4 oi, oj;
  oi.x = __hip_fp8_e4m3(vi.x * rsi).__x;
  oi.y = __hip_fp8_e4m3(vi.y * rsi).__x;
  oi.z = __hip_fp8_e4m3(vi.z * rsi).__x;
  oi.w = __hip_fp8_e4m3(vi.w * rsi).__x;
  oj.x = __hip_fp8_e4m3(vj.x * rsj).__x;
  oj.y = __hip_fp8_e4m3(vj.y * rsj).__x;
  oj.z = __hip_fp8_e4m3(vj.z * rsj).__x;
  oj.w = __hip_fp8_e4m3(vj.w * rsj).__x;
  ((uchar4*)(Z + (size_t)r * D))[tid] = oi;
  ((uchar4*)(Z + (size_t)(BS + r) * D))[tid] = oj;

  if (tid == 0) {
    dio[r] = tot[3] * rsi * rso;
    djo[r] = tot[4] * rsj * rso;
  }
}

// ---------------- kernel 2: upper-triangle S = Z Z^T, MX-fp8 32x32x64, depth-2 pipeline ----------------
// 128x128 tile, 4 waves as 2x2, wave-tile 64x64 = 2x2 MFMAs of 32x32x64 per K-step.
__global__ __launch_bounds__(256, 3) void gemm_lse_kernel(
    const unsigned char* __restrict__ Z,
    float* __restrict__ sumexp, float* __restrict__ pos) {
  __shared__ __align__(16) unsigned char lA[3][128 * BK];   // 3 x 8 KB
  __shared__ __align__(16) unsigned char lB[3][128 * BK];
  __shared__ float psumR[2][128];
  __shared__ float psumC[2][128];

  // XCD-bijective swizzle (2080 = 8 * 260)
  const int torig = blockIdx.x;
  const int t = (torig & 7) * (NBLK / 8) + (torig >> 3);

  // triangular decode: block t -> (bm, bn) with bm <= bn
  int bm = (int)((129.0f - sqrtf(16641.0f - 8.0f * (float)t)) * 0.5f);
  while ((bm + 1) * (129 - (bm + 1)) / 2 <= t) ++bm;
  while (bm * (129 - bm) / 2 > t) --bm;
  const int bn = bm + (t - bm * (129 - bm) / 2);
  const bool isDiag = (bm == bn);

  const int tid = threadIdx.x;
  const int lane = tid & 63, w = tid >> 6;
  const int wr = w >> 1, wc = w & 1;
  const int l31 = lane & 31, lh = lane >> 5;

  // ---- staging (both-sides swizzle, rule #21): LDS(row, ch) holds global chunk
  //      ch ^ ((row>>1)&3); dest is linear (tid*16), source pre-swizzled.
  const int srow = tid >> 2;                         // 0..63
  const int schunk = (tid & 3) ^ ((srow >> 1) & 3);  // (row>>1)&3, row=tid>>2
  const unsigned char* gA = Z + (size_t)(bm * 128 + srow) * D + schunk * 16;
  const unsigned char* gB = Z + (size_t)(bn * 128 + srow) * D + schunk * 16;

#define STAGE(buf)                                                \
  do {                                                            \
    gload_lds16(gA, &lA[buf][tid * 16]);                          \
    gload_lds16(gA + (size_t)64 * D, &lA[buf][tid * 16 + 4096]);  \
    gload_lds16(gB, &lB[buf][tid * 16]);                          \
    gload_lds16(gB + (size_t)64 * D, &lB[buf][tid * 16 + 4096]);  \
    gA += BK; gB += BK;                                           \
  } while (0)

  // ---- per-lane read offsets (loop-invariant). Fragment: row = tile0 + l31,
  //      K bytes [lh*32, lh*32+32) as two 16B chunks (c=0 lo, c=1 hi), each
  //      chunk XOR'd with the row's swizzle key.
  int offA[2][2], offB[2][2];
#pragma unroll
  for (int mi = 0; mi < 2; ++mi) {
    const int rowA = wr * 64 + mi * 32 + l31;
    const int rowB = wc * 64 + mi * 32 + l31;
    const int keyA = (rowA >> 1) & 3, keyB = (rowB >> 1) & 3;
#pragma unroll
    for (int c = 0; c < 2; ++c) {
      offA[mi][c] = rowA * BK + ((lh * 2 + c) ^ keyA) * 16;
      offB[mi][c] = rowB * BK + ((lh * 2 + c) ^ keyB) * 16;
    }
  }

  f32x16 acc[2][2] = {};

  STAGE(0);   // 4 loads in flight
  STAGE(1);   // 8 in flight

  for (int kt = 0; kt < NKT; ++kt) {
    const int cur = kt % 3;
    if (kt < NKT - 2) {
      STAGE((kt + 2) % 3);                  // 12 outstanding
      asm volatile("s_waitcnt vmcnt(8)");   // tile-kt's 4 loads complete
    } else if (kt == NKT - 2) {
      asm volatile("s_waitcnt vmcnt(4)");
    } else {
      asm volatile("s_waitcnt vmcnt(0)");
    }
    __builtin_amdgcn_s_barrier();
    __builtin_amdgcn_sched_barrier(0);

    const unsigned char* Ab = &lA[cur][0];
    const unsigned char* Bb = &lB[cur][0];
    i32x8 af[2], bf[2];
#pragma unroll
    for (int mi = 0; mi < 2; ++mi) {
      i32x4 lo = *(const i32x4*)(Ab + offA[mi][0]);
      i32x4 hi = *(const i32x4*)(Ab + offA[mi][1]);
      af[mi] = __builtin_shufflevector(lo, hi, 0, 1, 2, 3, 4, 5, 6, 7);
    }
#pragma unroll
    for (int ni = 0; ni < 2; ++ni) {
      i32x4 lo = *(const i32x4*)(Bb + offB[ni][0]);
      i32x4 hi = *(const i32x4*)(Bb + offB[ni][1]);
      bf[ni] = __builtin_shufflevector(lo, hi, 0, 1, 2, 3, 4, 5, 6, 7);
    }

#pragma unroll
    for (int mi = 0; mi < 2; ++mi)
#pragma unroll
      for (int ni = 0; ni < 2; ++ni)
        acc[mi][ni] = __builtin_amdgcn_mfma_scale_f32_32x32x64_f8f6f4(
            af[mi], bf[ni], acc[mi][ni],
            0, 0,                 // cbsz = fp8 e4m3 (A), blgp = fp8 e4m3 (B)
            0, 0x7F7F7F7F,        // opsel_a, scale_a = E8M0 127 -> 1.0
            0, 0x7F7F7F7F);       // opsel_b, scale_b

    __builtin_amdgcn_sched_barrier(0);
    __builtin_amdgcn_s_barrier();
  }
#undef STAGE

  // ---- epilogue: 32x32 C layout: col = l31, row = (r&3) + 8*(r>>2) + 4*lh
  const int brow = bm * 128, bcol = bn * 128;
  float cs[2] = {0.f, 0.f};
#pragma unroll
  for (int mi = 0; mi < 2; ++mi) {
#pragma unroll
    for (int r = 0; r < 16; ++r) {
      const int rit = (r & 3) + 8 * (r >> 2) + 4 * lh;
      const int gq = brow + wr * 64 + mi * 32 + rit;
      const int prt = gq ^ BS;
      float sse = 0.f;
#pragma unroll
      for (int ni = 0; ni < 2; ++ni) {
        const int gc = bcol + wc * 64 + ni * 32 + l31;
        const float v = acc[mi][ni][r];
        if (gc == prt) { pos[gq] = v; pos[gc] = v; }   // symmetric positive pair
        const float e = (gc != gq) ? __expf(v) : 0.f;  // exclude self-term
        sse += e;
        cs[ni] += e;
      }
      sse += __shfl_xor(sse, 1);
      sse += __shfl_xor(sse, 2);
      sse += __shfl_xor(sse, 4);
      sse += __shfl_xor(sse, 8);
      sse += __shfl_xor(sse, 16);
      if (l31 == 0) psumR[wc][wr * 64 + mi * 32 + rit] = sse;
    }
  }
  if (!isDiag) {
#pragma unroll
    for (int ni = 0; ni < 2; ++ni) {
      cs[ni] += __shfl_xor(cs[ni], 32);
      if (lh == 0) psumC[wr][wc * 64 + ni * 32 + l31] = cs[ni];
    }
  }
  __syncthreads();
  if (tid < 128) atomicAdd(&sumexp[brow + tid], psumR[0][tid] + psumR[1][tid]);
  if (!isDiag && tid < 128)
    atomicAdd(&sumexp[bcol + tid], psumC[0][tid] + psumC[1][tid]);
}

// ---------------- kernel 3: final reduction + KL ----------------
__global__ __launch_bounds__(256) void finalize_kernel(
    const float* __restrict__ sumexp, const float* __restrict__ pos,
    const float* __restrict__ dio, const float* __restrict__ djo,
    float* __restrict__ out) {
  const int tid = threadIdx.x;
  float s1 = 0.f, sa = 0.f, sb = 0.f;
  for (int q = tid; q < M2; q += 256) s1 += __logf(sumexp[q]) - pos[q];
  for (int r = tid; r < BS; r += 256) { sa += __expf(dio[r]); sb += __expf(djo[r]); }

  __shared__ float red[4][3];
  float v3[3] = {s1, sa, sb};
#pragma unroll
  for (int k = 0; k < 3; ++k)
#pragma unroll
    for (int o = 32; o; o >>= 1) v3[k] += __shfl_xor(v3[k], o);
  const int w = tid >> 6, lane = tid & 63;
  if (lane == 0) { red[w][0] = v3[0]; red[w][1] = v3[1]; red[w][2] = v3[2]; }
  __syncthreads();
  const float S1 = red[0][0] + red[1][0] + red[2][0] + red[3][0];
  const float A  = red[0][1] + red[1][1] + red[2][1] + red[3][1];
  const float B  = red[0][2] + red[1][2] + red[2][2] + red[3][2];
  const float logB = __logf(B);
  const float invA = 1.0f / A;

  float kl = 0.f;
  for (int r = tid; r < BS; r += 256) {
    const float lp = djo[r] - logB;            // log_softmax target
    kl += __expf(lp) * (lp - __expf(dio[r]) * invA);
  }
#pragma unroll
  for (int o = 32; o; o >>= 1) kl += __shfl_xor(kl, o);
  __shared__ float red2[4];
  if (lane == 0) red2[w] = kl;
  __syncthreads();
  if (tid == 0) {
    const float KL = red2[0] + red2[1] + red2[2] + red2[3];
    out[0] = S1 / (float)M2 + 0.5f * KL;
  }
}

extern "C" void kernel_launch(void* const* d_in, const int* in_sizes, int n_in,
                              void* d_out, int out_size, void* d_ws, size_t ws_size,
                              hipStream_t stream) {
  const float* zi = (const float*)d_in[0];
  const float* zj = (const float*)d_in[1];
  const float* zo = (const float*)d_in[2];
  char* ws = (char*)d_ws;
  unsigned char* Z = (unsigned char*)(ws + OFF_Z);
  float* sumexp = (float*)(ws + OFF_SUMEXP);
  float* pos    = (float*)(ws + OFF_POS);
  float* dio    = (float*)(ws + OFF_DIO);
  float* djo    = (float*)(ws + OFF_DJO);

  prep_kernel<<<BS, 256, 0, stream>>>(zi, zj, zo, Z, dio, djo, sumexp);
  gemm_lse_kernel<<<NBLK, 256, 0, stream>>>(Z, sumexp, pos);
  finalize_kernel<<<1, 256, 0, stream>>>(sumexp, pos, dio, djo, (float*)d_out);
}

// Round 7
// 228.396 us; speedup vs baseline: 1.3361x; 1.3361x over previous
//
#include <hip/hip_runtime.h>
#include <hip/hip_fp8.h>

typedef int   i32x4  __attribute__((ext_vector_type(4)));
typedef int   i32x8  __attribute__((ext_vector_type(8)));
typedef float f32x16 __attribute__((ext_vector_type(16)));

#define BS 4096
#define D 1024          // elements per row; also BYTES per row in fp8
#define M2 8192

#define BK 64           // K elements (= bytes) per K-step
#define NKT (D / BK)    // 16 K-steps
#define NT 64           // M2/128 tiles per dim
#define NBLK (NT * (NT + 1) / 2)   // 2080 upper-triangle blocks (2080 % 8 == 0)

// workspace layout (bytes)
#define OFF_Z      ((size_t)0)
#define OFF_SUMEXP ((size_t)M2 * D * 2)
#define OFF_POS    (OFF_SUMEXP + (size_t)M2 * 4)
#define OFF_DIO    (OFF_POS + (size_t)M2 * 4)
#define OFF_DJO    (OFF_DIO + (size_t)BS * 4)

static __device__ __forceinline__ void gload_lds16(const void* g, void* l) {
  __builtin_amdgcn_global_load_lds(
      (__attribute__((address_space(1))) void*)(uintptr_t)g,
      (__attribute__((address_space(3))) void*)(unsigned int)(uintptr_t)l,
      16, 0, 0);
}

// ---------------- kernel 1: normalize rows, emit fp8 Z, per-row dots, zero sumexp ----------------
__global__ __launch_bounds__(256) void prep_kernel(
    const float* __restrict__ zi, const float* __restrict__ zj,
    const float* __restrict__ zo, unsigned char* __restrict__ Z,
    float* __restrict__ dio, float* __restrict__ djo,
    float* __restrict__ sumexp) {
  const int r = blockIdx.x;
  const int tid = threadIdx.x;
  if (tid < 2) sumexp[2 * r + tid] = 0.f;
  const float4 vi = ((const float4*)(zi + (size_t)r * D))[tid];
  const float4 vj = ((const float4*)(zj + (size_t)r * D))[tid];
  const float4 vo = ((const float4*)(zo + (size_t)r * D))[tid];

  float s[5];
  s[0] = vi.x * vi.x + vi.y * vi.y + vi.z * vi.z + vi.w * vi.w;
  s[1] = vj.x * vj.x + vj.y * vj.y + vj.z * vj.z + vj.w * vj.w;
  s[2] = vo.x * vo.x + vo.y * vo.y + vo.z * vo.z + vo.w * vo.w;
  s[3] = vi.x * vo.x + vi.y * vo.y + vi.z * vo.z + vi.w * vo.w;
  s[4] = vj.x * vo.x + vj.y * vo.y + vj.z * vo.z + vj.w * vo.w;

#pragma unroll
  for (int k = 0; k < 5; ++k)
#pragma unroll
    for (int o = 32; o; o >>= 1) s[k] += __shfl_xor(s[k], o);

  __shared__ float red[4][5];
  const int w = tid >> 6, lane = tid & 63;
  if (lane == 0) {
#pragma unroll
    for (int k = 0; k < 5; ++k) red[w][k] = s[k];
  }
  __syncthreads();
  float tot[5];
#pragma unroll
  for (int k = 0; k < 5; ++k)
    tot[k] = red[0][k] + red[1][k] + red[2][k] + red[3][k];

  const float rsi = 1.0f / sqrtf(tot[0]);
  const float rsj = 1.0f / sqrtf(tot[1]);
  const float rso = 1.0f / sqrtf(tot[2]);

  uchar4 oi, oj;
  oi.x = __hip_fp8_e4m3(vi.x * rsi).__x;
  oi.y = __hip_fp8_e4m3(vi.y * rsi).__x;
  oi.z = __hip_fp8_e4m3(vi.z * rsi).__x;
  oi.w = __hip_fp8_e4m3(vi.w * rsi).__x;
  oj.x = __hip_fp8_e4m3(vj.x * rsj).__x;
  oj.y = __hip_fp8_e4m3(vj.y * rsj).__x;
  oj.z = __hip_fp8_e4m3(vj.z * rsj).__x;
  oj.w = __hip_fp8_e4m3(vj.w * rsj).__x;
  ((uchar4*)(Z + (size_t)r * D))[tid] = oi;
  ((uchar4*)(Z + (size_t)(BS + r) * D))[tid] = oj;

  if (tid == 0) {
    dio[r] = tot[3] * rsi * rso;
    djo[r] = tot[4] * rsj * rso;
  }
}

// ---------------- kernel 2: upper-triangle S = Z Z^T, MX-fp8 32x32x64, depth-2 pipeline ----------------
// 128x128 tile, 4 waves as 2x2, wave-tile 64x64 = 2x2 MFMAs of 32x32x64 per K-step.
// __launch_bounds__(256, 2): mfma_scale keeps C/D + v8i32 operands in ARCH VGPRs;
// at (256,3) the unified-file split gave only ~84 arch regs -> acc spilled to
// scratch (r6: WRITE_SIZE 626 MB, MfmaUtil 0.1%). (256,2) gives ~150+ arch regs.
__global__ __launch_bounds__(256, 2) void gemm_lse_kernel(
    const unsigned char* __restrict__ Z,
    float* __restrict__ sumexp, float* __restrict__ pos) {
  __shared__ __align__(16) unsigned char lA[3][128 * BK];   // 3 x 8 KB
  __shared__ __align__(16) unsigned char lB[3][128 * BK];
  __shared__ float psumR[2][128];
  __shared__ float psumC[2][128];

  // XCD-bijective swizzle (2080 = 8 * 260)
  const int torig = blockIdx.x;
  const int t = (torig & 7) * (NBLK / 8) + (torig >> 3);

  // triangular decode: block t -> (bm, bn) with bm <= bn
  int bm = (int)((129.0f - sqrtf(16641.0f - 8.0f * (float)t)) * 0.5f);
  while ((bm + 1) * (129 - (bm + 1)) / 2 <= t) ++bm;
  while (bm * (129 - bm) / 2 > t) --bm;
  const int bn = bm + (t - bm * (129 - bm) / 2);
  const bool isDiag = (bm == bn);

  const int tid = threadIdx.x;
  const int lane = tid & 63, w = tid >> 6;
  const int wr = w >> 1, wc = w & 1;
  const int l31 = lane & 31, lh = lane >> 5;

  // staging (both-sides swizzle): LDS(row, ch) holds global chunk ch ^ ((row>>1)&3)
  const int srow = tid >> 2;                         // 0..63
  const int schunk = (tid & 3) ^ ((srow >> 1) & 3);
  const unsigned char* gA = Z + (size_t)(bm * 128 + srow) * D + schunk * 16;
  const unsigned char* gB = Z + (size_t)(bn * 128 + srow) * D + schunk * 16;

#define STAGE(buf)                                                \
  do {                                                            \
    gload_lds16(gA, &lA[buf][tid * 16]);                          \
    gload_lds16(gA + (size_t)64 * D, &lA[buf][tid * 16 + 4096]);  \
    gload_lds16(gB, &lB[buf][tid * 16]);                          \
    gload_lds16(gB + (size_t)64 * D, &lB[buf][tid * 16 + 4096]);  \
    gA += BK; gB += BK;                                           \
  } while (0)

  // per-lane read offsets (loop-invariant); fragment row = tile0 + l31,
  // K bytes [lh*32, +32) as two 16B chunks, each XOR'd with the row's key
  int offA[2][2], offB[2][2];
#pragma unroll
  for (int mi = 0; mi < 2; ++mi) {
    const int rowA = wr * 64 + mi * 32 + l31;
    const int rowB = wc * 64 + mi * 32 + l31;
    const int keyA = (rowA >> 1) & 3, keyB = (rowB >> 1) & 3;
#pragma unroll
    for (int c = 0; c < 2; ++c) {
      offA[mi][c] = rowA * BK + ((lh * 2 + c) ^ keyA) * 16;
      offB[mi][c] = rowB * BK + ((lh * 2 + c) ^ keyB) * 16;
    }
  }

  f32x16 acc00 = {}, acc01 = {}, acc10 = {}, acc11 = {};

  STAGE(0);   // 4 loads in flight
  STAGE(1);   // 8 in flight

  for (int kt = 0; kt < NKT; ++kt) {
    const int cur = kt % 3;
    if (kt < NKT - 2) {
      STAGE((kt + 2) % 3);                  // 12 outstanding
      asm volatile("s_waitcnt vmcnt(8)");   // tile-kt's 4 loads complete
    } else if (kt == NKT - 2) {
      asm volatile("s_waitcnt vmcnt(4)");
    } else {
      asm volatile("s_waitcnt vmcnt(0)");
    }
    __builtin_amdgcn_s_barrier();
    __builtin_amdgcn_sched_barrier(0);

    const unsigned char* Ab = &lA[cur][0];
    const unsigned char* Bb = &lB[cur][0];
    i32x8 af[2], bf[2];
#pragma unroll
    for (int mi = 0; mi < 2; ++mi) {
      i32x4 lo = *(const i32x4*)(Ab + offA[mi][0]);
      i32x4 hi = *(const i32x4*)(Ab + offA[mi][1]);
      af[mi] = __builtin_shufflevector(lo, hi, 0, 1, 2, 3, 4, 5, 6, 7);
    }
#pragma unroll
    for (int ni = 0; ni < 2; ++ni) {
      i32x4 lo = *(const i32x4*)(Bb + offB[ni][0]);
      i32x4 hi = *(const i32x4*)(Bb + offB[ni][1]);
      bf[ni] = __builtin_shufflevector(lo, hi, 0, 1, 2, 3, 4, 5, 6, 7);
    }

    acc00 = __builtin_amdgcn_mfma_scale_f32_32x32x64_f8f6f4(
        af[0], bf[0], acc00, 0, 0, 0, 0x7F7F7F7F, 0, 0x7F7F7F7F);
    acc01 = __builtin_amdgcn_mfma_scale_f32_32x32x64_f8f6f4(
        af[0], bf[1], acc01, 0, 0, 0, 0x7F7F7F7F, 0, 0x7F7F7F7F);
    acc10 = __builtin_amdgcn_mfma_scale_f32_32x32x64_f8f6f4(
        af[1], bf[0], acc10, 0, 0, 0, 0x7F7F7F7F, 0, 0x7F7F7F7F);
    acc11 = __builtin_amdgcn_mfma_scale_f32_32x32x64_f8f6f4(
        af[1], bf[1], acc11, 0, 0, 0, 0x7F7F7F7F, 0, 0x7F7F7F7F);

    __builtin_amdgcn_sched_barrier(0);
    __builtin_amdgcn_s_barrier();
  }
#undef STAGE

  // epilogue: 32x32 C layout: col = l31, row = (r&3) + 8*(r>>2) + 4*lh
  const int brow = bm * 128, bcol = bn * 128;
  float cs[2] = {0.f, 0.f};
#pragma unroll
  for (int mi = 0; mi < 2; ++mi) {
#pragma unroll
    for (int r = 0; r < 16; ++r) {
      const int rit = (r & 3) + 8 * (r >> 2) + 4 * lh;
      const int gq = brow + wr * 64 + mi * 32 + rit;
      const int prt = gq ^ BS;
      float sse = 0.f;
#pragma unroll
      for (int ni = 0; ni < 2; ++ni) {
        const int gc = bcol + wc * 64 + ni * 32 + l31;
        const float v = (mi == 0) ? ((ni == 0) ? acc00[r] : acc01[r])
                                  : ((ni == 0) ? acc10[r] : acc11[r]);
        if (gc == prt) { pos[gq] = v; pos[gc] = v; }   // symmetric positive pair
        const float e = (gc != gq) ? __expf(v) : 0.f;  // exclude self-term
        sse += e;
        cs[ni] += e;
      }
      sse += __shfl_xor(sse, 1);
      sse += __shfl_xor(sse, 2);
      sse += __shfl_xor(sse, 4);
      sse += __shfl_xor(sse, 8);
      sse += __shfl_xor(sse, 16);
      if (l31 == 0) psumR[wc][wr * 64 + mi * 32 + rit] = sse;
    }
  }
  if (!isDiag) {
#pragma unroll
    for (int ni = 0; ni < 2; ++ni) {
      cs[ni] += __shfl_xor(cs[ni], 32);
      if (lh == 0) psumC[wr][wc * 64 + ni * 32 + l31] = cs[ni];
    }
  }
  __syncthreads();
  if (tid < 128) atomicAdd(&sumexp[brow + tid], psumR[0][tid] + psumR[1][tid]);
  if (!isDiag && tid < 128)
    atomicAdd(&sumexp[bcol + tid], psumC[0][tid] + psumC[1][tid]);
}

// ---------------- kernel 3: final reduction + KL ----------------
__global__ __launch_bounds__(256) void finalize_kernel(
    const float* __restrict__ sumexp, const float* __restrict__ pos,
    const float* __restrict__ dio, const float* __restrict__ djo,
    float* __restrict__ out) {
  const int tid = threadIdx.x;
  float s1 = 0.f, sa = 0.f, sb = 0.f;
  for (int q = tid; q < M2; q += 256) s1 += __logf(sumexp[q]) - pos[q];
  for (int r = tid; r < BS; r += 256) { sa += __expf(dio[r]); sb += __expf(djo[r]); }

  __shared__ float red[4][3];
  float v3[3] = {s1, sa, sb};
#pragma unroll
  for (int k = 0; k < 3; ++k)
#pragma unroll
    for (int o = 32; o; o >>= 1) v3[k] += __shfl_xor(v3[k], o);
  const int w = tid >> 6, lane = tid & 63;
  if (lane == 0) { red[w][0] = v3[0]; red[w][1] = v3[1]; red[w][2] = v3[2]; }
  __syncthreads();
  const float S1 = red[0][0] + red[1][0] + red[2][0] + red[3][0];
  const float A  = red[0][1] + red[1][1] + red[2][1] + red[3][1];
  const float B  = red[0][2] + red[1][2] + red[2][2] + red[3][2];
  const float logB = __logf(B);
  const float invA = 1.0f / A;

  float kl = 0.f;
  for (int r = tid; r < BS; r += 256) {
    const float lp = djo[r] - logB;            // log_softmax target
    kl += __expf(lp) * (lp - __expf(dio[r]) * invA);
  }
#pragma unroll
  for (int o = 32; o; o >>= 1) kl += __shfl_xor(kl, o);
  __shared__ float red2[4];
  if (lane == 0) red2[w] = kl;
  __syncthreads();
  if (tid == 0) {
    const float KL = red2[0] + red2[1] + red2[2] + red2[3];
    out[0] = S1 / (float)M2 + 0.5f * KL;
  }
}

extern "C" void kernel_launch(void* const* d_in, const int* in_sizes, int n_in,
                              void* d_out, int out_size, void* d_ws, size_t ws_size,
                              hipStream_t stream) {
  const float* zi = (const float*)d_in[0];
  const float* zj = (const float*)d_in[1];
  const float* zo = (const float*)d_in[2];
  char* ws = (char*)d_ws;
  unsigned char* Z = (unsigned char*)(ws + OFF_Z);
  float* sumexp = (float*)(ws + OFF_SUMEXP);
  float* pos    = (float*)(ws + OFF_POS);
  float* dio    = (float*)(ws + OFF_DIO);
  float* djo    = (float*)(ws + OFF_DJO);

  prep_kernel<<<BS, 256, 0, stream>>>(zi, zj, zo, Z, dio, djo, sumexp);
  gemm_lse_kernel<<<NBLK, 256, 0, stream>>>(Z, sumexp, pos);
  finalize_kernel<<<1, 256, 0, stream>>>(sumexp, pos, dio, djo, (float*)d_out);
}

// Round 8
// 104.167 us; speedup vs baseline: 2.9294x; 2.1926x over previous
//
#include <hip/hip_runtime.h>
#include <hip/hip_fp8.h>

typedef int   i32x4  __attribute__((ext_vector_type(4)));
typedef float f32x16 __attribute__((ext_vector_type(16)));

#define BS 4096
#define D 1024          // elements per row; also BYTES per row in fp8
#define M2 8192

#define BK 64           // K elements (= bytes) per K-step
#define NKT (D / BK)    // 16 K-steps
#define NT 64           // M2/128 tiles per dim
#define NBLK (NT * (NT + 1) / 2)   // 2080 upper-triangle blocks (2080 % 8 == 0)

// workspace layout (bytes)
#define OFF_Z      ((size_t)0)
#define OFF_SUMEXP ((size_t)M2 * D * 2)
#define OFF_POS    (OFF_SUMEXP + (size_t)M2 * 4)
#define OFF_DIO    (OFF_POS + (size_t)M2 * 4)
#define OFF_DJO    (OFF_DIO + (size_t)BS * 4)

static __device__ __forceinline__ void gload_lds16(const void* g, void* l) {
  __builtin_amdgcn_global_load_lds(
      (__attribute__((address_space(1))) void*)(uintptr_t)g,
      (__attribute__((address_space(3))) void*)(unsigned int)(uintptr_t)l,
      16, 0, 0);
}

// ---------------- kernel 1: normalize rows, emit fp8 Z, per-row dots, zero sumexp ----------------
__global__ __launch_bounds__(256) void prep_kernel(
    const float* __restrict__ zi, const float* __restrict__ zj,
    const float* __restrict__ zo, unsigned char* __restrict__ Z,
    float* __restrict__ dio, float* __restrict__ djo,
    float* __restrict__ sumexp) {
  const int r = blockIdx.x;
  const int tid = threadIdx.x;
  if (tid < 2) sumexp[2 * r + tid] = 0.f;
  const float4 vi = ((const float4*)(zi + (size_t)r * D))[tid];
  const float4 vj = ((const float4*)(zj + (size_t)r * D))[tid];
  const float4 vo = ((const float4*)(zo + (size_t)r * D))[tid];

  float s[5];
  s[0] = vi.x * vi.x + vi.y * vi.y + vi.z * vi.z + vi.w * vi.w;
  s[1] = vj.x * vj.x + vj.y * vj.y + vj.z * vj.z + vj.w * vj.w;
  s[2] = vo.x * vo.x + vo.y * vo.y + vo.z * vo.z + vo.w * vo.w;
  s[3] = vi.x * vo.x + vi.y * vo.y + vi.z * vo.z + vi.w * vo.w;
  s[4] = vj.x * vo.x + vj.y * vo.y + vj.z * vo.z + vj.w * vo.w;

#pragma unroll
  for (int k = 0; k < 5; ++k)
#pragma unroll
    for (int o = 32; o; o >>= 1) s[k] += __shfl_xor(s[k], o);

  __shared__ float red[4][5];
  const int w = tid >> 6, lane = tid & 63;
  if (lane == 0) {
#pragma unroll
    for (int k = 0; k < 5; ++k) red[w][k] = s[k];
  }
  __syncthreads();
  float tot[5];
#pragma unroll
  for (int k = 0; k < 5; ++k)
    tot[k] = red[0][k] + red[1][k] + red[2][k] + red[3][k];

  const float rsi = 1.0f / sqrtf(tot[0]);
  const float rsj = 1.0f / sqrtf(tot[1]);
  const float rso = 1.0f / sqrtf(tot[2]);

  uchar4 oi, oj;
  oi.x = __hip_fp8_e4m3(vi.x * rsi).__x;
  oi.y = __hip_fp8_e4m3(vi.y * rsi).__x;
  oi.z = __hip_fp8_e4m3(vi.z * rsi).__x;
  oi.w = __hip_fp8_e4m3(vi.w * rsi).__x;
  oj.x = __hip_fp8_e4m3(vj.x * rsj).__x;
  oj.y = __hip_fp8_e4m3(vj.y * rsj).__x;
  oj.z = __hip_fp8_e4m3(vj.z * rsj).__x;
  oj.w = __hip_fp8_e4m3(vj.w * rsj).__x;
  ((uchar4*)(Z + (size_t)r * D))[tid] = oi;
  ((uchar4*)(Z + (size_t)(BS + r) * D))[tid] = oj;

  if (tid == 0) {
    dio[r] = tot[3] * rsi * rso;
    djo[r] = tot[4] * rsj * rso;
  }
}

// ---------------- kernel 2: upper-triangle S = Z Z^T, fp8 32x32x16 (AGPR acc), depth-2 ----------------
// 128x128 tile, 4 waves as 2x2, wave-tile 64x64 = 2x2 of 32x32, 4 K-slices per K-step (BK=64).
// K-order freedom: any injective physical-byte->k-slot map works if A and B use the same map;
// each ds_read_b128 feeds two K=16 slices (lo/hi 8 bytes).
__global__ __launch_bounds__(256) void gemm_lse_kernel(
    const unsigned char* __restrict__ Z,
    float* __restrict__ sumexp, float* __restrict__ pos) {
  __shared__ __align__(16) unsigned char lA[3][128 * BK];   // 3 x 8 KB
  __shared__ __align__(16) unsigned char lB[3][128 * BK];
  __shared__ float psumR[2][128];
  __shared__ float psumC[2][128];

  // XCD-bijective swizzle (2080 = 8 * 260)
  const int torig = blockIdx.x;
  const int t = (torig & 7) * (NBLK / 8) + (torig >> 3);

  // triangular decode: block t -> (bm, bn) with bm <= bn
  int bm = (int)((129.0f - sqrtf(16641.0f - 8.0f * (float)t)) * 0.5f);
  while ((bm + 1) * (129 - (bm + 1)) / 2 <= t) ++bm;
  while (bm * (129 - bm) / 2 > t) --bm;
  const int bn = bm + (t - bm * (129 - bm) / 2);
  const bool isDiag = (bm == bn);

  const int tid = threadIdx.x;
  const int lane = tid & 63, w = tid >> 6;
  const int wr = w >> 1, wc = w & 1;
  const int l31 = lane & 31, lh = lane >> 5;

  // staging (both-sides swizzle): LDS pos p holds global chunk p ^ ((row>>1)&3)
  const int srow = tid >> 2;                         // 0..63
  const int schunk = (tid & 3) ^ ((srow >> 1) & 3);
  const unsigned char* gA = Z + (size_t)(bm * 128 + srow) * D + schunk * 16;
  const unsigned char* gB = Z + (size_t)(bn * 128 + srow) * D + schunk * 16;

#define STAGE(buf)                                                \
  do {                                                            \
    gload_lds16(gA, &lA[buf][tid * 16]);                          \
    gload_lds16(gA + (size_t)64 * D, &lA[buf][tid * 16 + 4096]);  \
    gload_lds16(gB, &lB[buf][tid * 16]);                          \
    gload_lds16(gB + (size_t)64 * D, &lB[buf][tid * 16 + 4096]);  \
    gA += BK; gB += BK;                                           \
  } while (0)

  // per-lane read offsets (loop-invariant); fragment row = tile0 + l31,
  // physical bytes [lh*32, +32) as two 16B chunks, each XOR'd with the row's key
  int offA[2][2], offB[2][2];
#pragma unroll
  for (int mi = 0; mi < 2; ++mi) {
    const int rowA = wr * 64 + mi * 32 + l31;
    const int rowB = wc * 64 + mi * 32 + l31;
    const int keyA = (rowA >> 1) & 3, keyB = (rowB >> 1) & 3;
#pragma unroll
    for (int c = 0; c < 2; ++c) {
      offA[mi][c] = rowA * BK + ((lh * 2 + c) ^ keyA) * 16;
      offB[mi][c] = rowB * BK + ((lh * 2 + c) ^ keyB) * 16;
    }
  }

  f32x16 acc00 = {}, acc01 = {}, acc10 = {}, acc11 = {};

  STAGE(0);   // 4 loads in flight
  STAGE(1);   // 8 in flight

  for (int kt = 0; kt < NKT; ++kt) {
    const int cur = kt % 3;
    if (kt < NKT - 2) {
      STAGE((kt + 2) % 3);                  // 12 outstanding
      asm volatile("s_waitcnt vmcnt(8)");   // tile-kt's 4 loads complete
    } else if (kt == NKT - 2) {
      asm volatile("s_waitcnt vmcnt(4)");
    } else {
      asm volatile("s_waitcnt vmcnt(0)");
    }
    __builtin_amdgcn_s_barrier();
    __builtin_amdgcn_sched_barrier(0);

    const unsigned char* Ab = &lA[cur][0];
    const unsigned char* Bb = &lB[cur][0];
    union { i32x4 v; long l[2]; } ra0, ra1, rb0, rb1;
    long aS[2][4], bS[2][4];
#pragma unroll
    for (int mi = 0; mi < 2; ++mi) {
      ra0.v = *(const i32x4*)(Ab + offA[mi][0]);
      ra1.v = *(const i32x4*)(Ab + offA[mi][1]);
      aS[mi][0] = ra0.l[0]; aS[mi][1] = ra0.l[1];
      aS[mi][2] = ra1.l[0]; aS[mi][3] = ra1.l[1];
    }
#pragma unroll
    for (int ni = 0; ni < 2; ++ni) {
      rb0.v = *(const i32x4*)(Bb + offB[ni][0]);
      rb1.v = *(const i32x4*)(Bb + offB[ni][1]);
      bS[ni][0] = rb0.l[0]; bS[ni][1] = rb0.l[1];
      bS[ni][2] = rb1.l[0]; bS[ni][3] = rb1.l[1];
    }

#pragma unroll
    for (int s = 0; s < 4; ++s) {
      acc00 = __builtin_amdgcn_mfma_f32_32x32x16_fp8_fp8(aS[0][s], bS[0][s], acc00, 0, 0, 0);
      acc01 = __builtin_amdgcn_mfma_f32_32x32x16_fp8_fp8(aS[0][s], bS[1][s], acc01, 0, 0, 0);
      acc10 = __builtin_amdgcn_mfma_f32_32x32x16_fp8_fp8(aS[1][s], bS[0][s], acc10, 0, 0, 0);
      acc11 = __builtin_amdgcn_mfma_f32_32x32x16_fp8_fp8(aS[1][s], bS[1][s], acc11, 0, 0, 0);
    }

    __builtin_amdgcn_sched_barrier(0);
    __builtin_amdgcn_s_barrier();
  }
#undef STAGE

  // epilogue: 32x32 C layout (r6/r7-verified): col = l31, row = (r&3) + 8*(r>>2) + 4*lh
  const int brow = bm * 128, bcol = bn * 128;
  float cs[2] = {0.f, 0.f};
#pragma unroll
  for (int mi = 0; mi < 2; ++mi) {
#pragma unroll
    for (int r = 0; r < 16; ++r) {
      const int rit = (r & 3) + 8 * (r >> 2) + 4 * lh;
      const int gq = brow + wr * 64 + mi * 32 + rit;
      const int prt = gq ^ BS;
      float sse = 0.f;
#pragma unroll
      for (int ni = 0; ni < 2; ++ni) {
        const int gc = bcol + wc * 64 + ni * 32 + l31;
        const float v = (mi == 0) ? ((ni == 0) ? acc00[r] : acc01[r])
                                  : ((ni == 0) ? acc10[r] : acc11[r]);
        if (gc == prt) { pos[gq] = v; pos[gc] = v; }   // symmetric positive pair
        const float e = (gc != gq) ? __expf(v) : 0.f;  // exclude self-term
        sse += e;
        cs[ni] += e;
      }
      sse += __shfl_xor(sse, 1);
      sse += __shfl_xor(sse, 2);
      sse += __shfl_xor(sse, 4);
      sse += __shfl_xor(sse, 8);
      sse += __shfl_xor(sse, 16);
      if (l31 == 0) psumR[wc][wr * 64 + mi * 32 + rit] = sse;
    }
  }
  if (!isDiag) {
#pragma unroll
    for (int ni = 0; ni < 2; ++ni) {
      cs[ni] += __shfl_xor(cs[ni], 32);
      if (lh == 0) psumC[wr][wc * 64 + ni * 32 + l31] = cs[ni];
    }
  }
  __syncthreads();
  if (tid < 128) atomicAdd(&sumexp[brow + tid], psumR[0][tid] + psumR[1][tid]);
  if (!isDiag && tid < 128)
    atomicAdd(&sumexp[bcol + tid], psumC[0][tid] + psumC[1][tid]);
}

// ---------------- kernel 3: final reduction + KL ----------------
__global__ __launch_bounds__(256) void finalize_kernel(
    const float* __restrict__ sumexp, const float* __restrict__ pos,
    const float* __restrict__ dio, const float* __restrict__ djo,
    float* __restrict__ out) {
  const int tid = threadIdx.x;
  float s1 = 0.f, sa = 0.f, sb = 0.f;
  for (int q = tid; q < M2; q += 256) s1 += __logf(sumexp[q]) - pos[q];
  for (int r = tid; r < BS; r += 256) { sa += __expf(dio[r]); sb += __expf(djo[r]); }

  __shared__ float red[4][3];
  float v3[3] = {s1, sa, sb};
#pragma unroll
  for (int k = 0; k < 3; ++k)
#pragma unroll
    for (int o = 32; o; o >>= 1) v3[k] += __shfl_xor(v3[k], o);
  const int w = tid >> 6, lane = tid & 63;
  if (lane == 0) { red[w][0] = v3[0]; red[w][1] = v3[1]; red[w][2] = v3[2]; }
  __syncthreads();
  const float S1 = red[0][0] + red[1][0] + red[2][0] + red[3][0];
  const float A  = red[0][1] + red[1][1] + red[2][1] + red[3][1];
  const float B  = red[0][2] + red[1][2] + red[2][2] + red[3][2];
  const float logB = __logf(B);
  const float invA = 1.0f / A;

  float kl = 0.f;
  for (int r = tid; r < BS; r += 256) {
    const float lp = djo[r] - logB;            // log_softmax target
    kl += __expf(lp) * (lp - __expf(dio[r]) * invA);
  }
#pragma unroll
  for (int o = 32; o; o >>= 1) kl += __shfl_xor(kl, o);
  __shared__ float red2[4];
  if (lane == 0) red2[w] = kl;
  __syncthreads();
  if (tid == 0) {
    const float KL = red2[0] + red2[1] + red2[2] + red2[3];
    out[0] = S1 / (float)M2 + 0.5f * KL;
  }
}

extern "C" void kernel_launch(void* const* d_in, const int* in_sizes, int n_in,
                              void* d_out, int out_size, void* d_ws, size_t ws_size,
                              hipStream_t stream) {
  const float* zi = (const float*)d_in[0];
  const float* zj = (const float*)d_in[1];
  const float* zo = (const float*)d_in[2];
  char* ws = (char*)d_ws;
  unsigned char* Z = (unsigned char*)(ws + OFF_Z);
  float* sumexp = (float*)(ws + OFF_SUMEXP);
  float* pos    = (float*)(ws + OFF_POS);
  float* dio    = (float*)(ws + OFF_DIO);
  float* djo    = (float*)(ws + OFF_DJO);

  prep_kernel<<<BS, 256, 0, stream>>>(zi, zj, zo, Z, dio, djo, sumexp);
  gemm_lse_kernel<<<NBLK, 256, 0, stream>>>(Z, sumexp, pos);
  finalize_kernel<<<1, 256, 0, stream>>>(sumexp, pos, dio, djo, (float*)d_out);
}